// Round 6
// baseline (143.519 us; speedup 1.0000x reference)
//
#include <hip/hip_runtime.h>

#define WAY 5
#define NQ 75
#define P 400              // 20*20 positions
#define PS (P*64)          // 25600 elements per sample
#define NPAIR (NQ*WAY)     // 375
#define TEMP_INV 0.2f      // 1/5.0
#define LOG2E 1.4426950408889634f

typedef unsigned short u16;
typedef _Float16 f16;
typedef __attribute__((ext_vector_type(8))) _Float16 f16x8;
typedef __attribute__((ext_vector_type(2))) __fp16 h16x2;   // cvt_pkrtz return type
typedef __attribute__((ext_vector_type(4))) float f32x4;

__device__ __forceinline__ float wave_sum(float v) {
  v += __shfl_xor(v, 1);  v += __shfl_xor(v, 2);  v += __shfl_xor(v, 4);
  v += __shfl_xor(v, 8);  v += __shfl_xor(v, 16); v += __shfl_xor(v, 32);
  return v;
}

// ---------------- prep: normalize_feature -> conv1x1 -> BN -> ReLU -> L2norm ----------------
// 800 blocks = 80 samples x 10 chunks of 40 positions, 8 waves each (5 pos/wave).
// Conv matvec uses 4 independent accumulators to break the serial fma chain.
__global__ __launch_bounds__(512) void prep_kernel(
    const float* __restrict__ spt, const float* __restrict__ qry,
    const float* __restrict__ conv_w,
    const float* __restrict__ bng, const float* __restrict__ bnb,
    const float* __restrict__ bnm, const float* __restrict__ bnv,
    f16* __restrict__ sA, f16* __restrict__ qA,
    float* __restrict__ snT, float* __restrict__ qnT)
{
  __shared__ float xt[40 * 65];
  __shared__ float wl[64 * 65];
  const int tid = threadIdx.x;
  const int n = blockIdx.x / 10, p0 = (blockIdx.x - n * 10) * 40;
  const float* src = (n < WAY) ? (spt + n * PS) : (qry + (n - WAY) * PS);
  for (int i = tid; i < 4096; i += 512) wl[(i >> 6) * 65 + (i & 63)] = conv_w[i];
  for (int i = tid; i < 2560; i += 512) {
    const int c = i / 40, pp = i - c * 40;
    xt[pp * 65 + c] = src[c * 400 + p0 + pp];          // coalesced 40-float runs
  }
  __syncthreads();
  const int lane = tid & 63, wv = tid >> 6;
  const float bs = bng[lane] * rsqrtf(bnv[lane] + 1e-5f);
  const float bm = bnm[lane], bb = bnb[lane];
  f16* dA; float* dN;
  if (n < WAY) { dA = sA + n * PS; dN = snT + n * PS; }
  else { const int m = n - WAY; dA = qA + m * PS; dN = qnT + m * PS; }
  for (int i = 0; i < 5; ++i) {
    const int p = wv * 5 + i;
    const float x = xt[p * 65 + lane];
    const float mu = wave_sum(x) * (1.0f / 64.0f);
    const float xm = x - mu;
    dN[(p0 + p) * 64 + lane] = xm;                     // [pos][c] f32 for pooling
    float y0 = 0.f, y1 = 0.f, y2 = 0.f, y3 = 0.f;
#pragma unroll
    for (int c = 0; c < 16; ++c) {
      y0 = fmaf(wl[lane * 65 + c],      __shfl(xm, c),      y0);
      y1 = fmaf(wl[lane * 65 + c + 16], __shfl(xm, c + 16), y1);
      y2 = fmaf(wl[lane * 65 + c + 32], __shfl(xm, c + 32), y2);
      y3 = fmaf(wl[lane * 65 + c + 48], __shfl(xm, c + 48), y3);
    }
    float y = (y0 + y1) + (y2 + y3);
    y = fmaf(y - bm, bs, bb);
    y = fmaxf(y, 0.f);
    const float n2 = wave_sum(y * y);
    const float rn = 1.0f / fmaxf(sqrtf(n2), 1e-8f);
    dA[(p0 + p) * 64 + lane] = (f16)(y * rn);          // fp16 RNE, values in [0, ~0.6]
  }
}

// ---------------- corr: X[a,b] = F1[a].F2[b]; per-b gaussnorm+softmax over a (400);
//                  attn[a] = sum_b w[a,b]; fused attention-weighted pooling. ----------------
// Block = (mode,pair), 8 waves, 52.8KB LDS -> 3 blocks/CU. F1 staged fp16 XOR-swizzled.
// Swapped MFMA: mfma(A=F2set, B=F1tile) -> lane l15 = a-index, (g,r) = b-column.
// attn accumulated via LDS float atomics; epilogue pools Fn with attn -> 64 floats.
__global__ __launch_bounds__(512, 3) void corr_kernel(
    const f16* __restrict__ sA, const f16* __restrict__ qA,
    const float* __restrict__ snT, const float* __restrict__ qnT,
    float* __restrict__ pooled)
{
  __shared__ f16 f1[25600];           // 51.2 KB, XOR-swizzled rows of 128B
  __shared__ float attn[400];         // 1.6 KB, atomically accumulated
  const int bid = blockIdx.x;
  const int mode = (bid >= NPAIR) ? 1 : 0;
  const int pair = mode ? (bid - NPAIR) : bid;
  const int q = pair / WAY, w = pair - q * WAY;
  const f16 *F1, *F2;
  if (!mode) { F1 = sA + w * PS; F2 = qA + q * PS; }
  else       { F1 = qA + q * PS; F2 = sA + w * PS; }

  const int tid = threadIdx.x, lane = tid & 63, wv = tid >> 6;
  const int l15 = lane & 15, g = (lane >> 4) & 3;

  // stage F1 into LDS, XOR-swizzled (rows of 128B; byte ^= (row&7)<<4)
  for (int i = tid; i < 3200; i += 512) {
    const unsigned sw = ((unsigned)(i * 16)) ^ ((((unsigned)i >> 3) & 7u) << 4);
    *(f16x8*)((char*)f1 + sw) = *(const f16x8*)(F1 + i * 8);
  }
  for (int i = tid; i < P; i += 512) attn[i] = 0.f;
  __syncthreads();

  const unsigned sx = ((unsigned)(l15 & 7)) << 4;
  const unsigned b0 = ((unsigned)(l15 * 128 + g * 16)) ^ sx;
  const unsigned b1 = ((unsigned)(l15 * 128 + g * 16 + 64)) ^ sx;
  const char* f1B = (const char*)f1;

  for (int s = 0; s < 4; ++s) {
    const int tile = wv + 8 * s;
    if (tile >= 25) continue;                       // wave-uniform
    // A-operand: this set's 16 b-columns (from global, once per set)
    const int aoffB = (tile * 16 + l15) * 64 + g * 8;
    const f16x8 Ah0 = *(const f16x8*)(F2 + aoffB);
    const f16x8 Ah1 = *(const f16x8*)(F2 + aoffB + 32);

    h16x2 packed[50];                               // X (later e), f16-packed
    float sum0 = 0.f, sum1 = 0.f, sum2 = 0.f, sum3 = 0.f;
    float ssq0 = 0.f, ssq1 = 0.f, ssq2 = 0.f, ssq3 = 0.f;
#pragma unroll
    for (int at = 0; at < 25; ++at) {
      const f16x8 Bh0 = *(const f16x8*)(f1B + at * 2048 + b0);
      const f16x8 Bh1 = *(const f16x8*)(f1B + at * 2048 + b1);
      f32x4 c = {0.f, 0.f, 0.f, 0.f};
      c = __builtin_amdgcn_mfma_f32_16x16x32_f16(Ah0, Bh0, c, 0, 0, 0);
      c = __builtin_amdgcn_mfma_f32_16x16x32_f16(Ah1, Bh1, c, 0, 0, 0);
      sum0 += c[0]; ssq0 = fmaf(c[0], c[0], ssq0);
      sum1 += c[1]; ssq1 = fmaf(c[1], c[1], ssq1);
      sum2 += c[2]; ssq2 = fmaf(c[2], c[2], ssq2);
      sum3 += c[3]; ssq3 = fmaf(c[3], c[3], ssq3);
      packed[2 * at]     = __builtin_amdgcn_cvt_pkrtz(c[0], c[1]);
      packed[2 * at + 1] = __builtin_amdgcn_cvt_pkrtz(c[2], c[3]);
    }
    // per-column (b) stats over the 400 a-values: shfl over l15 group
    float alpha[4], beta[4];
    {
      float sums[4] = {sum0, sum1, sum2, sum3};
      float ssqs[4] = {ssq0, ssq1, ssq2, ssq3};
#pragma unroll
      for (int r = 0; r < 4; ++r) {
        float s_ = sums[r], q_ = ssqs[r];
        s_ += __shfl_xor(s_, 1); s_ += __shfl_xor(s_, 2); s_ += __shfl_xor(s_, 4); s_ += __shfl_xor(s_, 8);
        q_ += __shfl_xor(q_, 1); q_ += __shfl_xor(q_, 2); q_ += __shfl_xor(q_, 4); q_ += __shfl_xor(q_, 8);
        const float m_ = s_ * (1.0f / 400.0f);
        float var = fmaf(-400.0f * m_, m_, q_) * (1.0f / 399.0f);  // ddof=1
        var = fmaxf(var, 0.f);
        const float a_ = rsqrtf(var + 1e-5f) * (TEMP_INV * LOG2E); // rstd/T, exp2 domain
        alpha[r] = a_;
        beta[r] = -m_ * a_;                                        // fold mean into fma
      }
    }
    // exp2 (no max-shift needed: |z|/T*log2e <= 5.8) + column sums
    float se0 = 0.f, se1 = 0.f, se2 = 0.f, se3 = 0.f;
#pragma unroll
    for (int at = 0; at < 25; ++at) {
      const h16x2 p0 = packed[2 * at], p1 = packed[2 * at + 1];
      const float e0 = __builtin_amdgcn_exp2f(fmaf((float)p0[0], alpha[0], beta[0]));
      const float e1 = __builtin_amdgcn_exp2f(fmaf((float)p0[1], alpha[1], beta[1]));
      const float e2 = __builtin_amdgcn_exp2f(fmaf((float)p1[0], alpha[2], beta[2]));
      const float e3 = __builtin_amdgcn_exp2f(fmaf((float)p1[1], alpha[3], beta[3]));
      se0 += e0; se1 += e1; se2 += e2; se3 += e3;
      packed[2 * at]     = __builtin_amdgcn_cvt_pkrtz(e0, e1);
      packed[2 * at + 1] = __builtin_amdgcn_cvt_pkrtz(e2, e3);
    }
    float inv[4];
    {
      float ses[4] = {se0, se1, se2, se3};
#pragma unroll
      for (int r = 0; r < 4; ++r) {
        float s_ = ses[r];
        s_ += __shfl_xor(s_, 1); s_ += __shfl_xor(s_, 2); s_ += __shfl_xor(s_, 4); s_ += __shfl_xor(s_, 8);
        inv[r] = 1.0f / s_;
      }
    }
    // attn[a] += sum over this set's 16 b-columns of e*inv (LDS float atomics)
#pragma unroll
    for (int at = 0; at < 25; ++at) {
      const h16x2 p0 = packed[2 * at], p1 = packed[2 * at + 1];
      float t = (float)p0[0] * inv[0];
      t = fmaf((float)p0[1], inv[1], t);
      t = fmaf((float)p1[0], inv[2], t);
      t = fmaf((float)p1[1], inv[3], t);
      t += __shfl_xor(t, 16); t += __shfl_xor(t, 32);
      if (lane < 16) atomicAdd(&attn[at * 16 + lane], t);
    }
  }
  __syncthreads();
  // fused pooling: pooled[c] = (1/400) * sum_a attn[a] * Fn[a][c]
  const float* Fn = mode ? (qnT + q * PS) : (snT + w * PS);
  float pacc = 0.f;
  for (int j = 0; j < 50; ++j) {
    const int a = wv * 50 + j;
    pacc = fmaf(attn[a], Fn[a * 64 + lane], pacc);
  }
  float* pbuf = (float*)f1;                          // f1 is dead; reuse as [8][64] f32
  pbuf[wv * 64 + lane] = pacc;
  __syncthreads();
  if (wv == 0) {
    float s_ = 0.f;
#pragma unroll
    for (int k = 0; k < 8; ++k) s_ += pbuf[k * 64 + lane];
    pooled[(mode * NPAIR + pair) * 64 + lane] = s_ * (1.0f / 400.0f);
  }
}

// ---------------- cosine: out[pair] = cos(spt_att, qry_att) * scale ----------------
__global__ __launch_bounds__(256) void cos_kernel(
    const float* __restrict__ pooled, const float* __restrict__ scale,
    float* __restrict__ out)
{
  const int pair = blockIdx.x * 4 + (threadIdx.x >> 6);
  const int lane = threadIdx.x & 63;
  if (pair >= NPAIR) return;
  const float sa = pooled[pair * 64 + lane];
  const float qa = pooled[(NPAIR + pair) * 64 + lane];
  const float d   = wave_sum(sa * qa);
  const float ns  = wave_sum(sa * sa);
  const float nq2 = wave_sum(qa * qa);
  if (lane == 0) {
    const float den = fmaxf(sqrtf(ns), 1e-6f) * fmaxf(sqrtf(nq2), 1e-6f);
    out[pair] = d / den * scale[0];
  }
}

extern "C" void kernel_launch(void* const* d_in, const int* in_sizes, int n_in,
                              void* d_out, int out_size, void* d_ws, size_t ws_size,
                              hipStream_t stream) {
  const float* spt    = (const float*)d_in[0];
  const float* qry    = (const float*)d_in[1];
  const float* conv_w = (const float*)d_in[2];
  const float* bng    = (const float*)d_in[3];
  const float* bnb    = (const float*)d_in[4];
  const float* bnm    = (const float*)d_in[5];
  const float* bnv    = (const float*)d_in[6];
  const float* scale  = (const float*)d_in[7];
  float* out = (float*)d_out;

  char* p = (char*)d_ws;
  f16* sA = (f16*)p;      p += (size_t)WAY * PS * 2;
  f16* qA = (f16*)p;      p += (size_t)NQ * PS * 2;
  float* snT = (float*)p;     p += (size_t)WAY * PS * 4;
  float* qnT = (float*)p;     p += (size_t)NQ * PS * 4;
  float* pooled = (float*)p;  p += (size_t)2 * NPAIR * 64 * 4;

  prep_kernel<<<dim3(800), dim3(512), 0, stream>>>(
      spt, qry, conv_w, bng, bnb, bnm, bnv, sA, qA, snT, qnT);
  corr_kernel<<<dim3(2 * NPAIR), dim3(512), 0, stream>>>(
      sA, qA, snT, qnT, pooled);
  cos_kernel<<<dim3((NPAIR + 3) / 4), dim3(256), 0, stream>>>(
      pooled, scale, out);
}

// Round 7
// 116.716 us; speedup vs baseline: 1.2297x; 1.2297x over previous
//
#include <hip/hip_runtime.h>

#define WAY 5
#define NQ 75
#define P 400              // 20*20 positions
#define PS (P*64)          // 25600 elements per sample
#define NPAIR (NQ*WAY)     // 375
#define TEMP_INV 0.2f      // 1/5.0
#define LOG2E 1.4426950408889634f

typedef unsigned short u16;
typedef _Float16 f16;
typedef __attribute__((ext_vector_type(8))) _Float16 f16x8;
typedef __attribute__((ext_vector_type(2))) __fp16 h16x2;   // cvt_pkrtz return type
typedef __attribute__((ext_vector_type(4))) float f32x4;

__device__ __forceinline__ float wave_sum(float v) {
  v += __shfl_xor(v, 1);  v += __shfl_xor(v, 2);  v += __shfl_xor(v, 4);
  v += __shfl_xor(v, 8);  v += __shfl_xor(v, 16); v += __shfl_xor(v, 32);
  return v;
}

// ---------------- prep: normalize_feature -> conv1x1 -> BN -> ReLU -> L2norm ----------------
// 800 blocks = 80 samples x 10 chunks of 40 positions, 8 waves each (5 pos/wave).
// Conv matvec uses 4 independent accumulators to break the serial fma chain.
__global__ __launch_bounds__(512) void prep_kernel(
    const float* __restrict__ spt, const float* __restrict__ qry,
    const float* __restrict__ conv_w,
    const float* __restrict__ bng, const float* __restrict__ bnb,
    const float* __restrict__ bnm, const float* __restrict__ bnv,
    f16* __restrict__ sA, f16* __restrict__ qA,
    float* __restrict__ snT, float* __restrict__ qnT)
{
  __shared__ float xt[40 * 65];
  __shared__ float wl[64 * 65];
  const int tid = threadIdx.x;
  const int n = blockIdx.x / 10, p0 = (blockIdx.x - n * 10) * 40;
  const float* src = (n < WAY) ? (spt + n * PS) : (qry + (n - WAY) * PS);
  for (int i = tid; i < 4096; i += 512) wl[(i >> 6) * 65 + (i & 63)] = conv_w[i];
  for (int i = tid; i < 2560; i += 512) {
    const int c = i / 40, pp = i - c * 40;
    xt[pp * 65 + c] = src[c * 400 + p0 + pp];          // coalesced 40-float runs
  }
  __syncthreads();
  const int lane = tid & 63, wv = tid >> 6;
  const float bs = bng[lane] * rsqrtf(bnv[lane] + 1e-5f);
  const float bm = bnm[lane], bb = bnb[lane];
  f16* dA; float* dN;
  if (n < WAY) { dA = sA + n * PS; dN = snT + n * PS; }
  else { const int m = n - WAY; dA = qA + m * PS; dN = qnT + m * PS; }
  for (int i = 0; i < 5; ++i) {
    const int p = wv * 5 + i;
    const float x = xt[p * 65 + lane];
    const float mu = wave_sum(x) * (1.0f / 64.0f);
    const float xm = x - mu;
    dN[(p0 + p) * 64 + lane] = xm;                     // [pos][c] f32 for pooling
    float y0 = 0.f, y1 = 0.f, y2 = 0.f, y3 = 0.f;
#pragma unroll
    for (int c = 0; c < 16; ++c) {
      y0 = fmaf(wl[lane * 65 + c],      __shfl(xm, c),      y0);
      y1 = fmaf(wl[lane * 65 + c + 16], __shfl(xm, c + 16), y1);
      y2 = fmaf(wl[lane * 65 + c + 32], __shfl(xm, c + 32), y2);
      y3 = fmaf(wl[lane * 65 + c + 48], __shfl(xm, c + 48), y3);
    }
    float y = (y0 + y1) + (y2 + y3);
    y = fmaf(y - bm, bs, bb);
    y = fmaxf(y, 0.f);
    const float n2 = wave_sum(y * y);
    const float rn = 1.0f / fmaxf(sqrtf(n2), 1e-8f);
    dA[(p0 + p) * 64 + lane] = (f16)(y * rn);          // fp16 RNE, values in [0, ~0.6]
  }
}

// ---------------- corr: X[a,b] = F1[a].F2[b]; per-b gaussnorm+softmax over a (400);
//                  attn[a] = sum_b w[a,b]; fused attention-weighted pooling. ----------------
// Round-5 structure (private attn_sm rows, no atomics, (512,4), 64KB LDS -> 2 blocks/CU)
// + exp2 with folded log2e + fused pooling epilogue (pool kernel deleted).
__global__ __launch_bounds__(512, 4) void corr_kernel(
    const f16* __restrict__ sA, const f16* __restrict__ qA,
    const float* __restrict__ snT, const float* __restrict__ qnT,
    float* __restrict__ pooled)
{
  __shared__ f16 f1[25600];           // 51.2 KB, XOR-swizzled rows of 128B
  __shared__ float attn_sm[8 * 400];  // 12.8 KB, per-wave private rows
  const int bid = blockIdx.x;
  const int mode = (bid >= NPAIR) ? 1 : 0;
  const int pair = mode ? (bid - NPAIR) : bid;
  const int q = pair / WAY, w = pair - q * WAY;
  const f16 *F1, *F2;
  if (!mode) { F1 = sA + w * PS; F2 = qA + q * PS; }
  else       { F1 = qA + q * PS; F2 = sA + w * PS; }

  const int tid = threadIdx.x, lane = tid & 63, wv = tid >> 6;
  const int l15 = lane & 15, g = (lane >> 4) & 3;

  // stage F1 into LDS, XOR-swizzled (rows of 128B; byte ^= (row&7)<<4)
  for (int i = tid; i < 3200; i += 512) {
    const unsigned sw = ((unsigned)(i * 16)) ^ ((((unsigned)i >> 3) & 7u) << 4);
    *(f16x8*)((char*)f1 + sw) = *(const f16x8*)(F1 + i * 8);
  }
  for (int i = lane; i < P; i += 64) attn_sm[wv * P + i] = 0.f;
  __syncthreads();

  const unsigned sx = ((unsigned)(l15 & 7)) << 4;
  const unsigned b0 = ((unsigned)(l15 * 128 + g * 16)) ^ sx;
  const unsigned b1 = ((unsigned)(l15 * 128 + g * 16 + 64)) ^ sx;
  const char* f1B = (const char*)f1;

  for (int s = 0; s < 4; ++s) {
    const int tile = wv + 8 * s;
    if (tile >= 25) continue;                       // wave-uniform
    // A-operand: this set's 16 b-columns (from global, once per set)
    const int aoffB = (tile * 16 + l15) * 64 + g * 8;
    const f16x8 Ah0 = *(const f16x8*)(F2 + aoffB);
    const f16x8 Ah1 = *(const f16x8*)(F2 + aoffB + 32);

    h16x2 packed[50];                               // X (later e), f16-packed
    float sum0 = 0.f, sum1 = 0.f, sum2 = 0.f, sum3 = 0.f;
    float ssq0 = 0.f, ssq1 = 0.f, ssq2 = 0.f, ssq3 = 0.f;
#pragma unroll
    for (int at = 0; at < 25; ++at) {
      const f16x8 Bh0 = *(const f16x8*)(f1B + at * 2048 + b0);
      const f16x8 Bh1 = *(const f16x8*)(f1B + at * 2048 + b1);
      f32x4 c = {0.f, 0.f, 0.f, 0.f};
      c = __builtin_amdgcn_mfma_f32_16x16x32_f16(Ah0, Bh0, c, 0, 0, 0);
      c = __builtin_amdgcn_mfma_f32_16x16x32_f16(Ah1, Bh1, c, 0, 0, 0);
      sum0 += c[0]; ssq0 = fmaf(c[0], c[0], ssq0);
      sum1 += c[1]; ssq1 = fmaf(c[1], c[1], ssq1);
      sum2 += c[2]; ssq2 = fmaf(c[2], c[2], ssq2);
      sum3 += c[3]; ssq3 = fmaf(c[3], c[3], ssq3);
      packed[2 * at]     = __builtin_amdgcn_cvt_pkrtz(c[0], c[1]);
      packed[2 * at + 1] = __builtin_amdgcn_cvt_pkrtz(c[2], c[3]);
    }
    // per-column (b) stats over the 400 a-values: shfl over l15 group
    float alpha[4], beta[4];
    {
      float sums[4] = {sum0, sum1, sum2, sum3};
      float ssqs[4] = {ssq0, ssq1, ssq2, ssq3};
#pragma unroll
      for (int r = 0; r < 4; ++r) {
        float s_ = sums[r], q_ = ssqs[r];
        s_ += __shfl_xor(s_, 1); s_ += __shfl_xor(s_, 2); s_ += __shfl_xor(s_, 4); s_ += __shfl_xor(s_, 8);
        q_ += __shfl_xor(q_, 1); q_ += __shfl_xor(q_, 2); q_ += __shfl_xor(q_, 4); q_ += __shfl_xor(q_, 8);
        const float m_ = s_ * (1.0f / 400.0f);
        float var = fmaf(-400.0f * m_, m_, q_) * (1.0f / 399.0f);  // ddof=1
        var = fmaxf(var, 0.f);
        const float a_ = rsqrtf(var + 1e-5f) * (TEMP_INV * LOG2E); // rstd/T, exp2 domain
        alpha[r] = a_;
        beta[r] = -m_ * a_;                                        // fold mean into fma
      }
    }
    // exp2 (no max-shift needed: |z|/T*log2e <= 5.8) + column sums
    float se0 = 0.f, se1 = 0.f, se2 = 0.f, se3 = 0.f;
#pragma unroll
    for (int at = 0; at < 25; ++at) {
      const h16x2 p0 = packed[2 * at], p1 = packed[2 * at + 1];
      const float e0 = __builtin_amdgcn_exp2f(fmaf((float)p0[0], alpha[0], beta[0]));
      const float e1 = __builtin_amdgcn_exp2f(fmaf((float)p0[1], alpha[1], beta[1]));
      const float e2 = __builtin_amdgcn_exp2f(fmaf((float)p1[0], alpha[2], beta[2]));
      const float e3 = __builtin_amdgcn_exp2f(fmaf((float)p1[1], alpha[3], beta[3]));
      se0 += e0; se1 += e1; se2 += e2; se3 += e3;
      packed[2 * at]     = __builtin_amdgcn_cvt_pkrtz(e0, e1);
      packed[2 * at + 1] = __builtin_amdgcn_cvt_pkrtz(e2, e3);
    }
    float inv[4];
    {
      float ses[4] = {se0, se1, se2, se3};
#pragma unroll
      for (int r = 0; r < 4; ++r) {
        float s_ = ses[r];
        s_ += __shfl_xor(s_, 1); s_ += __shfl_xor(s_, 2); s_ += __shfl_xor(s_, 4); s_ += __shfl_xor(s_, 8);
        inv[r] = 1.0f / s_;
      }
    }
    // attn[a] += sum over this set's 16 b-columns of e*inv (private row, no atomics)
#pragma unroll
    for (int at = 0; at < 25; ++at) {
      const h16x2 p0 = packed[2 * at], p1 = packed[2 * at + 1];
      float t = (float)p0[0] * inv[0];
      t = fmaf((float)p0[1], inv[1], t);
      t = fmaf((float)p1[0], inv[2], t);
      t = fmaf((float)p1[1], inv[3], t);
      t += __shfl_xor(t, 16); t += __shfl_xor(t, 32);
      if (lane < 16) attn_sm[wv * P + at * 16 + lane] += t;
    }
  }
  __syncthreads();
  // merge the 8 private rows into row 0 (each a handled by exactly one thread)
  for (int a = tid; a < P; a += 512) {
    float s_ = attn_sm[a];
#pragma unroll
    for (int k = 1; k < 8; ++k) s_ += attn_sm[k * P + a];
    attn_sm[a] = s_;
  }
  __syncthreads();
  // fused pooling: pooled[c] = (1/400) * sum_a attn[a] * Fn[a][c]
  const float* Fn = mode ? (qnT + q * PS) : (snT + w * PS);
  float pa0 = 0.f, pa1 = 0.f;
  for (int j = 0; j < 50; j += 2) {
    const int a = wv * 50 + j;
    pa0 = fmaf(attn_sm[a],     Fn[a * 64 + lane],      pa0);
    pa1 = fmaf(attn_sm[a + 1], Fn[(a + 1) * 64 + lane], pa1);
  }
  float* pbuf = (float*)f1;                          // f1 is dead; reuse as [8][64] f32
  pbuf[wv * 64 + lane] = pa0 + pa1;
  __syncthreads();
  if (wv == 0) {
    float s_ = 0.f;
#pragma unroll
    for (int k = 0; k < 8; ++k) s_ += pbuf[k * 64 + lane];
    pooled[(mode * NPAIR + pair) * 64 + lane] = s_ * (1.0f / 400.0f);
  }
}

// ---------------- cosine: out[pair] = cos(spt_att, qry_att) * scale ----------------
__global__ __launch_bounds__(256) void cos_kernel(
    const float* __restrict__ pooled, const float* __restrict__ scale,
    float* __restrict__ out)
{
  const int pair = blockIdx.x * 4 + (threadIdx.x >> 6);
  const int lane = threadIdx.x & 63;
  if (pair >= NPAIR) return;
  const float sa = pooled[pair * 64 + lane];
  const float qa = pooled[(NPAIR + pair) * 64 + lane];
  const float d   = wave_sum(sa * qa);
  const float ns  = wave_sum(sa * sa);
  const float nq2 = wave_sum(qa * qa);
  if (lane == 0) {
    const float den = fmaxf(sqrtf(ns), 1e-6f) * fmaxf(sqrtf(nq2), 1e-6f);
    out[pair] = d / den * scale[0];
  }
}

extern "C" void kernel_launch(void* const* d_in, const int* in_sizes, int n_in,
                              void* d_out, int out_size, void* d_ws, size_t ws_size,
                              hipStream_t stream) {
  const float* spt    = (const float*)d_in[0];
  const float* qry    = (const float*)d_in[1];
  const float* conv_w = (const float*)d_in[2];
  const float* bng    = (const float*)d_in[3];
  const float* bnb    = (const float*)d_in[4];
  const float* bnm    = (const float*)d_in[5];
  const float* bnv    = (const float*)d_in[6];
  const float* scale  = (const float*)d_in[7];
  float* out = (float*)d_out;

  char* p = (char*)d_ws;
  f16* sA = (f16*)p;      p += (size_t)WAY * PS * 2;
  f16* qA = (f16*)p;      p += (size_t)NQ * PS * 2;
  float* snT = (float*)p;     p += (size_t)WAY * PS * 4;
  float* qnT = (float*)p;     p += (size_t)NQ * PS * 4;
  float* pooled = (float*)p;  p += (size_t)2 * NPAIR * 64 * 4;

  prep_kernel<<<dim3(800), dim3(512), 0, stream>>>(
      spt, qry, conv_w, bng, bnb, bnm, bnv, sA, qA, snT, qnT);
  corr_kernel<<<dim3(2 * NPAIR), dim3(512), 0, stream>>>(
      sA, qA, snT, qnT, pooled);
  cos_kernel<<<dim3((NPAIR + 3) / 4), dim3(256), 0, stream>>>(
      pooled, scale, out);
}

// Round 8
// 88.899 us; speedup vs baseline: 1.6144x; 1.3129x over previous
//
#include <hip/hip_runtime.h>

#define WAY 5
#define NQ 75
#define P 400              // 20*20 positions
#define PS (P*64)          // 25600 elements per sample
#define NPAIR (NQ*WAY)     // 375
#define TEMP_INV 0.2f      // 1/5.0
#define LOG2E 1.4426950408889634f

typedef unsigned short u16;
typedef _Float16 f16;
typedef __attribute__((ext_vector_type(8))) _Float16 f16x8;
typedef __attribute__((ext_vector_type(2))) __fp16 h16x2;   // cvt_pkrtz return type
typedef __attribute__((ext_vector_type(4))) float f32x4;

__device__ __forceinline__ float wave_sum(float v) {
  v += __shfl_xor(v, 1);  v += __shfl_xor(v, 2);  v += __shfl_xor(v, 4);
  v += __shfl_xor(v, 8);  v += __shfl_xor(v, 16); v += __shfl_xor(v, 32);
  return v;
}

// ---------------- prep: normalize_feature -> conv1x1 -> BN -> ReLU -> L2norm ----------------
// 800 blocks = 80 samples x 10 chunks of 40 positions, 8 waves each (5 pos/wave).
// Lane = output channel. Weights held in 16 f32x4 regs/lane; x-row read via
// same-address (broadcast) ds_read_b128; mean-subtract folded: y = W.x - mu*sum(W).
__global__ __launch_bounds__(512) void prep_kernel(
    const float* __restrict__ spt, const float* __restrict__ qry,
    const float* __restrict__ conv_w,
    const float* __restrict__ bng, const float* __restrict__ bnb,
    const float* __restrict__ bnm, const float* __restrict__ bnv,
    f16* __restrict__ sA, f16* __restrict__ qA,
    float* __restrict__ snT, float* __restrict__ qnT)
{
  __shared__ float xt[40 * 68];                        // stride 68 floats = 272B (16B-aligned)
  const int tid = threadIdx.x;
  const int n = blockIdx.x / 10, p0 = (blockIdx.x - n * 10) * 40;
  const float* src = (n < WAY) ? (spt + n * PS) : (qry + (n - WAY) * PS);
  const int lane = tid & 63, wv = tid >> 6;

  // per-lane weight row W[lane][0..63] (conv_w is [o][c] row-major)
  f32x4 wr[16];
#pragma unroll
  for (int j = 0; j < 16; ++j) wr[j] = *(const f32x4*)(conv_w + lane * 64 + j * 4);
  float wsum = 0.f;
#pragma unroll
  for (int j = 0; j < 16; ++j) wsum += (wr[j][0] + wr[j][1]) + (wr[j][2] + wr[j][3]);

  for (int i = tid; i < 2560; i += 512) {
    const int c = i / 40, pp = i - c * 40;
    xt[pp * 68 + c] = src[c * 400 + p0 + pp];          // coalesced 40-float runs
  }
  __syncthreads();

  const float bs = bng[lane] * rsqrtf(bnv[lane] + 1e-5f);
  const float bm = bnm[lane], bb = bnb[lane];
  f16* dA; float* dN;
  if (n < WAY) { dA = sA + n * PS; dN = snT + n * PS; }
  else { const int m = n - WAY; dA = qA + m * PS; dN = qnT + m * PS; }

  for (int i = 0; i < 5; ++i) {
    const int p = wv * 5 + i;
    const float x = xt[p * 68 + lane];
    const float mu = wave_sum(x) * (1.0f / 64.0f);
    dN[(p0 + p) * 64 + lane] = x - mu;                 // [pos][c] f32 for pooling
    float y0 = 0.f, y1 = 0.f, y2 = 0.f, y3 = 0.f;
#pragma unroll
    for (int j = 0; j < 16; ++j) {
      const f32x4 xv = *(const f32x4*)&xt[p * 68 + j * 4];  // broadcast (same addr all lanes)
      y0 = fmaf(wr[j][0], xv[0], y0);
      y1 = fmaf(wr[j][1], xv[1], y1);
      y2 = fmaf(wr[j][2], xv[2], y2);
      y3 = fmaf(wr[j][3], xv[3], y3);
    }
    float y = ((y0 + y1) + (y2 + y3)) - mu * wsum;     // == W.(x - mu)
    y = fmaf(y - bm, bs, bb);
    y = fmaxf(y, 0.f);
    const float n2 = wave_sum(y * y);
    const float rn = 1.0f / fmaxf(sqrtf(n2), 1e-8f);
    dA[(p0 + p) * 64 + lane] = (f16)(y * rn);          // fp16 RNE
  }
}

// ---------------- corr: X[a,b] = F1[a].F2[b]; per-b gaussnorm+softmax over a (400);
//                  attn[a] = sum_b w[a,b]; fused attention-weighted pooling. ----------------
// Block = (mode,pair), 8 waves, 51.2KB LDS. Swapped MFMA: lane l15 = a, (g,r) = b-col.
// Per-wave attn kept in 25 registers (no LDS RMW / shfl in hot loop); merged via
// the dead f1 buffer at the end; pooling fused.
__global__ __launch_bounds__(512, 4) void corr_kernel(
    const f16* __restrict__ sA, const f16* __restrict__ qA,
    const float* __restrict__ snT, const float* __restrict__ qnT,
    float* __restrict__ pooled)
{
  __shared__ f16 f1[25600];           // 51.2 KB, XOR-swizzled rows of 128B
  const int bid = blockIdx.x;
  const int mode = (bid >= NPAIR) ? 1 : 0;
  const int pair = mode ? (bid - NPAIR) : bid;
  const int q = pair / WAY, w = pair - q * WAY;
  const f16 *F1, *F2;
  if (!mode) { F1 = sA + w * PS; F2 = qA + q * PS; }
  else       { F1 = qA + q * PS; F2 = sA + w * PS; }

  const int tid = threadIdx.x, lane = tid & 63, wv = tid >> 6;
  const int l15 = lane & 15, g = (lane >> 4) & 3;

  // stage F1 into LDS, XOR-swizzled (rows of 128B; byte ^= (row&7)<<4)
  for (int i = tid; i < 3200; i += 512) {
    const unsigned sw = ((unsigned)(i * 16)) ^ ((((unsigned)i >> 3) & 7u) << 4);
    *(f16x8*)((char*)f1 + sw) = *(const f16x8*)(F1 + i * 8);
  }
  __syncthreads();

  const unsigned sx = ((unsigned)(l15 & 7)) << 4;
  const unsigned b0 = ((unsigned)(l15 * 128 + g * 16)) ^ sx;
  const unsigned b1 = ((unsigned)(l15 * 128 + g * 16 + 64)) ^ sx;
  const char* f1B = (const char*)f1;

  float av[25];                       // per-lane attn partials (g-group slice)
#pragma unroll
  for (int t = 0; t < 25; ++t) av[t] = 0.f;

  for (int s = 0; s < 4; ++s) {
    const int tile = wv + 8 * s;
    if (tile >= 25) continue;                       // wave-uniform
    // A-operand: this set's 16 b-columns (from global, once per set)
    const int aoffB = (tile * 16 + l15) * 64 + g * 8;
    const f16x8 Ah0 = *(const f16x8*)(F2 + aoffB);
    const f16x8 Ah1 = *(const f16x8*)(F2 + aoffB + 32);

    h16x2 packed[50];                               // X (later e), f16-packed
    float sum0 = 0.f, sum1 = 0.f, sum2 = 0.f, sum3 = 0.f;
    float ssq0 = 0.f, ssq1 = 0.f, ssq2 = 0.f, ssq3 = 0.f;
#pragma unroll
    for (int at = 0; at < 25; ++at) {
      const f16x8 Bh0 = *(const f16x8*)(f1B + at * 2048 + b0);
      const f16x8 Bh1 = *(const f16x8*)(f1B + at * 2048 + b1);
      f32x4 c = {0.f, 0.f, 0.f, 0.f};
      c = __builtin_amdgcn_mfma_f32_16x16x32_f16(Ah0, Bh0, c, 0, 0, 0);
      c = __builtin_amdgcn_mfma_f32_16x16x32_f16(Ah1, Bh1, c, 0, 0, 0);
      sum0 += c[0]; ssq0 = fmaf(c[0], c[0], ssq0);
      sum1 += c[1]; ssq1 = fmaf(c[1], c[1], ssq1);
      sum2 += c[2]; ssq2 = fmaf(c[2], c[2], ssq2);
      sum3 += c[3]; ssq3 = fmaf(c[3], c[3], ssq3);
      packed[2 * at]     = __builtin_amdgcn_cvt_pkrtz(c[0], c[1]);
      packed[2 * at + 1] = __builtin_amdgcn_cvt_pkrtz(c[2], c[3]);
    }
    // per-column (b) stats over the 400 a-values: shfl over l15 group
    float alpha[4], beta[4];
    {
      float sums[4] = {sum0, sum1, sum2, sum3};
      float ssqs[4] = {ssq0, ssq1, ssq2, ssq3};
#pragma unroll
      for (int r = 0; r < 4; ++r) {
        float s_ = sums[r], q_ = ssqs[r];
        s_ += __shfl_xor(s_, 1); s_ += __shfl_xor(s_, 2); s_ += __shfl_xor(s_, 4); s_ += __shfl_xor(s_, 8);
        q_ += __shfl_xor(q_, 1); q_ += __shfl_xor(q_, 2); q_ += __shfl_xor(q_, 4); q_ += __shfl_xor(q_, 8);
        const float m_ = s_ * (1.0f / 400.0f);
        float var = fmaf(-400.0f * m_, m_, q_) * (1.0f / 399.0f);  // ddof=1
        var = fmaxf(var, 0.f);
        const float a_ = rsqrtf(var + 1e-5f) * (TEMP_INV * LOG2E); // rstd/T, exp2 domain
        alpha[r] = a_;
        beta[r] = -m_ * a_;                                        // fold mean into fma
      }
    }
    // exp2 (no max-shift needed: |z|/T*log2e <= 5.8) + column sums
    float se0 = 0.f, se1 = 0.f, se2 = 0.f, se3 = 0.f;
#pragma unroll
    for (int at = 0; at < 25; ++at) {
      const h16x2 p0 = packed[2 * at], p1 = packed[2 * at + 1];
      const float e0 = __builtin_amdgcn_exp2f(fmaf((float)p0[0], alpha[0], beta[0]));
      const float e1 = __builtin_amdgcn_exp2f(fmaf((float)p0[1], alpha[1], beta[1]));
      const float e2 = __builtin_amdgcn_exp2f(fmaf((float)p1[0], alpha[2], beta[2]));
      const float e3 = __builtin_amdgcn_exp2f(fmaf((float)p1[1], alpha[3], beta[3]));
      se0 += e0; se1 += e1; se2 += e2; se3 += e3;
      packed[2 * at]     = __builtin_amdgcn_cvt_pkrtz(e0, e1);
      packed[2 * at + 1] = __builtin_amdgcn_cvt_pkrtz(e2, e3);
    }
    float inv[4];
    {
      float ses[4] = {se0, se1, se2, se3};
#pragma unroll
      for (int r = 0; r < 4; ++r) {
        float s_ = ses[r];
        s_ += __shfl_xor(s_, 1); s_ += __shfl_xor(s_, 2); s_ += __shfl_xor(s_, 4); s_ += __shfl_xor(s_, 8);
        inv[r] = 1.0f / s_;
      }
    }
    // attn partial: av[at] += sum over this lane's 4 b-columns of e*inv (registers only)
#pragma unroll
    for (int at = 0; at < 25; ++at) {
      const h16x2 p0 = packed[2 * at], p1 = packed[2 * at + 1];
      float t = (float)p0[0] * inv[0];
      t = fmaf((float)p0[1], inv[1], t);
      t = fmaf((float)p1[0], inv[2], t);
      t = fmaf((float)p1[1], inv[3], t);
      av[at] += t;
    }
  }
  // combine the 4 g-groups once per wave
#pragma unroll
  for (int at = 0; at < 25; ++at) {
    float v = av[at];
    v += __shfl_xor(v, 16); v += __shfl_xor(v, 32);
    av[at] = v;
  }
  __syncthreads();                                   // all waves done reading f1
  float* marea = (float*)f1;                         // reuse dead f1: [8][400] f32 + pbuf
  if (lane < 16) {
#pragma unroll
    for (int at = 0; at < 25; ++at) marea[wv * 400 + at * 16 + lane] = av[at];
  }
  __syncthreads();
  // merge the 8 private rows into row 0
  for (int a = tid; a < P; a += 512) {
    float s_ = marea[a];
#pragma unroll
    for (int k = 1; k < 8; ++k) s_ += marea[k * 400 + a];
    marea[a] = s_;
  }
  __syncthreads();
  // fused pooling: pooled[c] = (1/400) * sum_a attn[a] * Fn[a][c]
  const float* Fn = mode ? (qnT + q * PS) : (snT + w * PS);
  float pa0 = 0.f, pa1 = 0.f;
  for (int j = 0; j < 50; j += 2) {
    const int a = wv * 50 + j;
    pa0 = fmaf(marea[a],     Fn[a * 64 + lane],       pa0);
    pa1 = fmaf(marea[a + 1], Fn[(a + 1) * 64 + lane], pa1);
  }
  float* pbuf = marea + 512;                         // dead region (rows 1+)
  pbuf[wv * 64 + lane] = pa0 + pa1;
  __syncthreads();
  if (wv == 0) {
    float s_ = 0.f;
#pragma unroll
    for (int k = 0; k < 8; ++k) s_ += pbuf[k * 64 + lane];
    pooled[(mode * NPAIR + pair) * 64 + lane] = s_ * (1.0f / 400.0f);
  }
}

// ---------------- cosine: out[pair] = cos(spt_att, qry_att) * scale ----------------
__global__ __launch_bounds__(256) void cos_kernel(
    const float* __restrict__ pooled, const float* __restrict__ scale,
    float* __restrict__ out)
{
  const int pair = blockIdx.x * 4 + (threadIdx.x >> 6);
  const int lane = threadIdx.x & 63;
  if (pair >= NPAIR) return;
  const float sa = pooled[pair * 64 + lane];
  const float qa = pooled[(NPAIR + pair) * 64 + lane];
  const float d   = wave_sum(sa * qa);
  const float ns  = wave_sum(sa * sa);
  const float nq2 = wave_sum(qa * qa);
  if (lane == 0) {
    const float den = fmaxf(sqrtf(ns), 1e-6f) * fmaxf(sqrtf(nq2), 1e-6f);
    out[pair] = d / den * scale[0];
  }
}

extern "C" void kernel_launch(void* const* d_in, const int* in_sizes, int n_in,
                              void* d_out, int out_size, void* d_ws, size_t ws_size,
                              hipStream_t stream) {
  const float* spt    = (const float*)d_in[0];
  const float* qry    = (const float*)d_in[1];
  const float* conv_w = (const float*)d_in[2];
  const float* bng    = (const float*)d_in[3];
  const float* bnb    = (const float*)d_in[4];
  const float* bnm    = (const float*)d_in[5];
  const float* bnv    = (const float*)d_in[6];
  const float* scale  = (const float*)d_in[7];
  float* out = (float*)d_out;

  char* p = (char*)d_ws;
  f16* sA = (f16*)p;      p += (size_t)WAY * PS * 2;
  f16* qA = (f16*)p;      p += (size_t)NQ * PS * 2;
  float* snT = (float*)p;     p += (size_t)WAY * PS * 4;
  float* qnT = (float*)p;     p += (size_t)NQ * PS * 4;
  float* pooled = (float*)p;  p += (size_t)2 * NPAIR * 64 * 4;

  prep_kernel<<<dim3(800), dim3(512), 0, stream>>>(
      spt, qry, conv_w, bng, bnb, bnm, bnv, sA, qA, snT, qnT);
  corr_kernel<<<dim3(2 * NPAIR), dim3(512), 0, stream>>>(
      sA, qA, snT, qnT, pooled);
  cos_kernel<<<dim3((NPAIR + 3) / 4), dim3(256), 0, stream>>>(
      pooled, scale, out);
}

// Round 9
// 84.688 us; speedup vs baseline: 1.6947x; 1.0497x over previous
//
#include <hip/hip_runtime.h>
#include <hip/hip_fp16.h>

#define WAY 5
#define NQ 75
#define P 400              // 20*20 positions
#define PS (P*64)          // 25600 elements per sample
#define NPAIR (NQ*WAY)     // 375
#define TEMP_INV 0.2f      // 1/5.0
#define LOG2E 1.4426950408889634f

typedef unsigned short u16;
typedef _Float16 f16;
typedef __attribute__((ext_vector_type(8))) _Float16 f16x8;
typedef __attribute__((ext_vector_type(2))) _Float16 F16x2;
typedef __attribute__((ext_vector_type(2))) __fp16 h16x2;   // cvt_pkrtz return type
typedef __attribute__((ext_vector_type(4))) float f32x4;

__device__ __forceinline__ float wave_sum(float v) {
  v += __shfl_xor(v, 1);  v += __shfl_xor(v, 2);  v += __shfl_xor(v, 4);
  v += __shfl_xor(v, 8);  v += __shfl_xor(v, 16); v += __shfl_xor(v, 32);
  return v;
}

__device__ __forceinline__ __half2 pk2(float a, float b) {
  h16x2 t = __builtin_amdgcn_cvt_pkrtz(a, b);
  return __builtin_bit_cast(__half2, t);
}
__device__ __forceinline__ float hdot2(__half2 a, __half2 b, float c) {
  return __builtin_amdgcn_fdot2(__builtin_bit_cast(F16x2, a),
                                __builtin_bit_cast(F16x2, b), c, false);
}

// ---------------- prep: normalize_feature -> conv1x1 -> BN -> ReLU -> L2norm ----------------
// 800 blocks = 80 samples x 10 chunks of 40 positions, 8 waves each (5 pos/wave).
// Lane = output channel. Weights held in 16 f32x4 regs/lane; x-row read via
// same-address (broadcast) ds_read_b128; mean-subtract folded: y = W.x - mu*sum(W).
__global__ __launch_bounds__(512) void prep_kernel(
    const float* __restrict__ spt, const float* __restrict__ qry,
    const float* __restrict__ conv_w,
    const float* __restrict__ bng, const float* __restrict__ bnb,
    const float* __restrict__ bnm, const float* __restrict__ bnv,
    f16* __restrict__ sA, f16* __restrict__ qA,
    float* __restrict__ snT, float* __restrict__ qnT)
{
  __shared__ float xt[40 * 68];                        // stride 68 floats = 272B (16B-aligned)
  const int tid = threadIdx.x;
  const int n = blockIdx.x / 10, p0 = (blockIdx.x - n * 10) * 40;
  const float* src = (n < WAY) ? (spt + n * PS) : (qry + (n - WAY) * PS);
  const int lane = tid & 63, wv = tid >> 6;

  // per-lane weight row W[lane][0..63] (conv_w is [o][c] row-major)
  f32x4 wr[16];
#pragma unroll
  for (int j = 0; j < 16; ++j) wr[j] = *(const f32x4*)(conv_w + lane * 64 + j * 4);
  float wsum = 0.f;
#pragma unroll
  for (int j = 0; j < 16; ++j) wsum += (wr[j][0] + wr[j][1]) + (wr[j][2] + wr[j][3]);

  for (int i = tid; i < 2560; i += 512) {
    const int c = i / 40, pp = i - c * 40;
    xt[pp * 68 + c] = src[c * 400 + p0 + pp];          // coalesced 40-float runs
  }
  __syncthreads();

  const float bs = bng[lane] * rsqrtf(bnv[lane] + 1e-5f);
  const float bm = bnm[lane], bb = bnb[lane];
  f16* dA; float* dN;
  if (n < WAY) { dA = sA + n * PS; dN = snT + n * PS; }
  else { const int m = n - WAY; dA = qA + m * PS; dN = qnT + m * PS; }

  for (int i = 0; i < 5; ++i) {
    const int p = wv * 5 + i;
    const float x = xt[p * 68 + lane];
    const float mu = wave_sum(x) * (1.0f / 64.0f);
    dN[(p0 + p) * 64 + lane] = x - mu;                 // [pos][c] f32 for pooling
    float y0 = 0.f, y1 = 0.f, y2 = 0.f, y3 = 0.f;
#pragma unroll
    for (int j = 0; j < 16; ++j) {
      const f32x4 xv = *(const f32x4*)&xt[p * 68 + j * 4];  // broadcast (same addr all lanes)
      y0 = fmaf(wr[j][0], xv[0], y0);
      y1 = fmaf(wr[j][1], xv[1], y1);
      y2 = fmaf(wr[j][2], xv[2], y2);
      y3 = fmaf(wr[j][3], xv[3], y3);
    }
    float y = ((y0 + y1) + (y2 + y3)) - mu * wsum;     // == W.(x - mu)
    y = fmaf(y - bm, bs, bb);
    y = fmaxf(y, 0.f);
    const float n2 = wave_sum(y * y);
    const float rn = 1.0f / fmaxf(sqrtf(n2), 1e-8f);
    dA[(p0 + p) * 64 + lane] = (f16)(y * rn);          // fp16 RNE
  }
}

// ---------------- corr: X[a,b] = F1[a].F2[b]; per-b gaussnorm+softmax over a (400);
//                  attn[a] = sum_b w[a,b]; fused attention-weighted pooling. ----------------
// Block = (mode,pair), 8 waves, 51.2KB LDS. Swapped MFMA: lane l15 = a, (g,r) = b-col.
// X state packed by a-PAIRS per column r -> per-column reductions via v_dot2_f32_f16,
// exp via packed __hfma2 + h2exp2, attn contribution via packed hfma chain (f32 accum).
__global__ __launch_bounds__(512, 4) void corr_kernel(
    const f16* __restrict__ sA, const f16* __restrict__ qA,
    const float* __restrict__ snT, const float* __restrict__ qnT,
    float* __restrict__ pooled)
{
  __shared__ f16 f1[25600];           // 51.2 KB, XOR-swizzled rows of 128B
  const int bid = blockIdx.x;
  const int mode = (bid >= NPAIR) ? 1 : 0;
  const int pair = mode ? (bid - NPAIR) : bid;
  const int q = pair / WAY, w = pair - q * WAY;
  const f16 *F1, *F2;
  if (!mode) { F1 = sA + w * PS; F2 = qA + q * PS; }
  else       { F1 = qA + q * PS; F2 = sA + w * PS; }

  const int tid = threadIdx.x, lane = tid & 63, wv = tid >> 6;
  const int l15 = lane & 15, g = (lane >> 4) & 3;

  // stage F1 into LDS, XOR-swizzled (rows of 128B; byte ^= (row&7)<<4)
  for (int i = tid; i < 3200; i += 512) {
    const unsigned sw = ((unsigned)(i * 16)) ^ ((((unsigned)i >> 3) & 7u) << 4);
    *(f16x8*)((char*)f1 + sw) = *(const f16x8*)(F1 + i * 8);
  }
  __syncthreads();

  const unsigned sx = ((unsigned)(l15 & 7)) << 4;
  const unsigned b0 = ((unsigned)(l15 * 128 + g * 16)) ^ sx;
  const unsigned b1 = ((unsigned)(l15 * 128 + g * 16 + 64)) ^ sx;
  const char* f1B = (const char*)f1;

  const __half2 one2 = __float2half2_rn(1.0f);
  const __half2 m10  = __halves2half2(__float2half_rn(1.0f), __float2half_rn(0.0f));

  float av[25];                       // per-lane attn partials (g-group slice), f32
#pragma unroll
  for (int t = 0; t < 25; ++t) av[t] = 0.f;

  for (int s = 0; s < 4; ++s) {
    const int tile = wv + 8 * s;
    if (tile >= 25) continue;                       // wave-uniform
    // A-operand: this set's 16 b-columns (from global, once per set)
    const int aoffB = (tile * 16 + l15) * 64 + g * 8;
    const f16x8 Ah0 = *(const f16x8*)(F2 + aoffB);
    const f16x8 Ah1 = *(const f16x8*)(F2 + aoffB + 32);

    __half2 px[4][13];                              // px[r][t] = X(a=2t, a=2t+1) for col r
    float sum[4] = {0.f, 0.f, 0.f, 0.f};
    float ssq[4] = {0.f, 0.f, 0.f, 0.f};
#pragma unroll
    for (int t = 0; t < 12; ++t) {
      const int at0 = 2 * t, at1 = 2 * t + 1;
      const f16x8 B00 = *(const f16x8*)(f1B + at0 * 2048 + b0);
      const f16x8 B01 = *(const f16x8*)(f1B + at0 * 2048 + b1);
      const f16x8 B10 = *(const f16x8*)(f1B + at1 * 2048 + b0);
      const f16x8 B11 = *(const f16x8*)(f1B + at1 * 2048 + b1);
      f32x4 c0 = {0.f, 0.f, 0.f, 0.f};
      c0 = __builtin_amdgcn_mfma_f32_16x16x32_f16(Ah0, B00, c0, 0, 0, 0);
      c0 = __builtin_amdgcn_mfma_f32_16x16x32_f16(Ah1, B01, c0, 0, 0, 0);
      f32x4 c1 = {0.f, 0.f, 0.f, 0.f};
      c1 = __builtin_amdgcn_mfma_f32_16x16x32_f16(Ah0, B10, c1, 0, 0, 0);
      c1 = __builtin_amdgcn_mfma_f32_16x16x32_f16(Ah1, B11, c1, 0, 0, 0);
#pragma unroll
      for (int r = 0; r < 4; ++r) {
        const __half2 p = pk2(c0[r], c1[r]);
        px[r][t] = p;
        sum[r] = hdot2(p, one2, sum[r]);
        ssq[r] = hdot2(p, p, ssq[r]);
      }
    }
    { // tail a-tile 24 (second half zero-padded)
      const f16x8 B00 = *(const f16x8*)(f1B + 24 * 2048 + b0);
      const f16x8 B01 = *(const f16x8*)(f1B + 24 * 2048 + b1);
      f32x4 c0 = {0.f, 0.f, 0.f, 0.f};
      c0 = __builtin_amdgcn_mfma_f32_16x16x32_f16(Ah0, B00, c0, 0, 0, 0);
      c0 = __builtin_amdgcn_mfma_f32_16x16x32_f16(Ah1, B01, c0, 0, 0, 0);
#pragma unroll
      for (int r = 0; r < 4; ++r) {
        const __half2 p = pk2(c0[r], 0.f);
        px[r][12] = p;
        sum[r] = hdot2(p, one2, sum[r]);            // +0 from pad
        ssq[r] = hdot2(p, p, ssq[r]);               // +0 from pad
      }
    }
    // per-column (b) stats over the 400 a-values: shfl over l15 group
    __half2 a2[4], b2[4];
#pragma unroll
    for (int r = 0; r < 4; ++r) {
      float s_ = sum[r], q_ = ssq[r];
      s_ += __shfl_xor(s_, 1); s_ += __shfl_xor(s_, 2); s_ += __shfl_xor(s_, 4); s_ += __shfl_xor(s_, 8);
      q_ += __shfl_xor(q_, 1); q_ += __shfl_xor(q_, 2); q_ += __shfl_xor(q_, 4); q_ += __shfl_xor(q_, 8);
      const float m_ = s_ * (1.0f / 400.0f);
      float var = fmaf(-400.0f * m_, m_, q_) * (1.0f / 399.0f);  // ddof=1
      var = fmaxf(var, 0.f);
      const float al = rsqrtf(var + 1e-5f) * (TEMP_INV * LOG2E); // rstd/T, exp2 domain
      a2[r] = __float2half2_rn(al);
      b2[r] = __float2half2_rn(-m_ * al);                        // fold mean
    }
    // packed exp2 + per-column e-sums (f32 via dot2); tail masked (pad would give 2^beta)
    float se[4] = {0.f, 0.f, 0.f, 0.f};
#pragma unroll
    for (int t = 0; t < 13; ++t) {
      const __half2 msk = (t == 12) ? m10 : one2;
#pragma unroll
      for (int r = 0; r < 4; ++r) {
        const __half2 e = h2exp2(__hfma2(px[r][t], a2[r], b2[r]));
        px[r][t] = e;
        se[r] = hdot2(e, msk, se[r]);
      }
    }
    __half2 iv2[4];
#pragma unroll
    for (int r = 0; r < 4; ++r) {
      float s_ = se[r];
      s_ += __shfl_xor(s_, 1); s_ += __shfl_xor(s_, 2); s_ += __shfl_xor(s_, 4); s_ += __shfl_xor(s_, 8);
      iv2[r] = __float2half2_rn(1.0f / s_);
    }
    // attn partials: av[a] += sum_r e[a,r]*inv[r]  (packed 4-term chain, f32 accumulate)
#pragma unroll
    for (int t = 0; t < 13; ++t) {
      __half2 acc = __hmul2(px[3][t], iv2[3]);
      acc = __hfma2(px[2][t], iv2[2], acc);
      acc = __hfma2(px[1][t], iv2[1], acc);
      acc = __hfma2(px[0][t], iv2[0], acc);
      av[2 * t] += __low2float(acc);
      if (t < 12) av[2 * t + 1] += __high2float(acc);
    }
  }
  // combine the 4 g-groups once per wave
#pragma unroll
  for (int at = 0; at < 25; ++at) {
    float v = av[at];
    v += __shfl_xor(v, 16); v += __shfl_xor(v, 32);
    av[at] = v;
  }
  __syncthreads();                                   // all waves done reading f1
  float* marea = (float*)f1;                         // reuse dead f1: [8][400] f32 + pbuf
  if (lane < 16) {
#pragma unroll
    for (int at = 0; at < 25; ++at) marea[wv * 400 + at * 16 + lane] = av[at];
  }
  __syncthreads();
  // merge the 8 private rows into row 0
  for (int a = tid; a < P; a += 512) {
    float s_ = marea[a];
#pragma unroll
    for (int k = 1; k < 8; ++k) s_ += marea[k * 400 + a];
    marea[a] = s_;
  }
  __syncthreads();
  // fused pooling: pooled[c] = (1/400) * sum_a attn[a] * Fn[a][c]
  const float* Fn = mode ? (qnT + q * PS) : (snT + w * PS);
  float pa0 = 0.f, pa1 = 0.f;
  for (int j = 0; j < 50; j += 2) {
    const int a = wv * 50 + j;
    pa0 = fmaf(marea[a],     Fn[a * 64 + lane],       pa0);
    pa1 = fmaf(marea[a + 1], Fn[(a + 1) * 64 + lane], pa1);
  }
  float* pbuf = marea + 512;                         // dead region (rows 1+)
  pbuf[wv * 64 + lane] = pa0 + pa1;
  __syncthreads();
  if (wv == 0) {
    float s_ = 0.f;
#pragma unroll
    for (int k = 0; k < 8; ++k) s_ += pbuf[k * 64 + lane];
    pooled[(mode * NPAIR + pair) * 64 + lane] = s_ * (1.0f / 400.0f);
  }
}

// ---------------- cosine: out[pair] = cos(spt_att, qry_att) * scale ----------------
__global__ __launch_bounds__(256) void cos_kernel(
    const float* __restrict__ pooled, const float* __restrict__ scale,
    float* __restrict__ out)
{
  const int pair = blockIdx.x * 4 + (threadIdx.x >> 6);
  const int lane = threadIdx.x & 63;
  if (pair >= NPAIR) return;
  const float sa = pooled[pair * 64 + lane];
  const float qa = pooled[(NPAIR + pair) * 64 + lane];
  const float d   = wave_sum(sa * qa);
  const float ns  = wave_sum(sa * sa);
  const float nq2 = wave_sum(qa * qa);
  if (lane == 0) {
    const float den = fmaxf(sqrtf(ns), 1e-6f) * fmaxf(sqrtf(nq2), 1e-6f);
    out[pair] = d / den * scale[0];
  }
}

extern "C" void kernel_launch(void* const* d_in, const int* in_sizes, int n_in,
                              void* d_out, int out_size, void* d_ws, size_t ws_size,
                              hipStream_t stream) {
  const float* spt    = (const float*)d_in[0];
  const float* qry    = (const float*)d_in[1];
  const float* conv_w = (const float*)d_in[2];
  const float* bng    = (const float*)d_in[3];
  const float* bnb    = (const float*)d_in[4];
  const float* bnm    = (const float*)d_in[5];
  const float* bnv    = (const float*)d_in[6];
  const float* scale  = (const float*)d_in[7];
  float* out = (float*)d_out;

  char* p = (char*)d_ws;
  f16* sA = (f16*)p;      p += (size_t)WAY * PS * 2;
  f16* qA = (f16*)p;      p += (size_t)NQ * PS * 2;
  float* snT = (float*)p;     p += (size_t)WAY * PS * 4;
  float* qnT = (float*)p;     p += (size_t)NQ * PS * 4;
  float* pooled = (float*)p;  p += (size_t)2 * NPAIR * 64 * 4;

  prep_kernel<<<dim3(800), dim3(512), 0, stream>>>(
      spt, qry, conv_w, bng, bnb, bnm, bnv, sA, qA, snT, qnT);
  corr_kernel<<<dim3(2 * NPAIR), dim3(512), 0, stream>>>(
      sA, qA, snT, qnT, pooled);
  cos_kernel<<<dim3((NPAIR + 3) / 4), dim3(256), 0, stream>>>(
      pooled, scale, out);
}